// Round 3
// baseline (3217.289 us; speedup 1.0000x reference)
//
#include <hip/hip_runtime.h>
#include <hip/hip_bf16.h>

// ChebNet classifier: 3x ChebConv(K=6) + pool + linear. fp32 internal.
// Round 3: runtime dtype detection (fp32 vs bf16 float tensors) — device-side
// flag derived from x's bit patterns; all float-input consumers branch on it
// uniformly (explicit if/else so no speculative wrong-width loads).
// W k-slice offsets passed in ELEMENTS (koff) so byte math is dtype-local.

#define N0 200000
#define N1 50000
#define N2 12500
#define KCH 6
#define NCLS 10

typedef __hip_bfloat16 bf16;
static __device__ __forceinline__ float b2f(bf16 v) { return __bfloat162float(v); }

// ---------------- dtype detection ----------------
// fp32 words: bits[14:7] are random mantissa bits (~7% land in [0x30,0x43]).
// packed bf16: bits[14:7] = even element's exponent (~100% in band for N(0,1)).
__global__ void detect_k(const unsigned int* __restrict__ xb, int* __restrict__ flag) {
    __shared__ int cs;
    int t = threadIdx.x;
    if (t == 0) cs = 0;
    __syncthreads();
    unsigned w = xb[t];
    unsigned e = (w >> 7) & 0xFFu;
    if (e >= 0x30u && e <= 0x43u) atomicAdd(&cs, 1);
    __syncthreads();
    if (t == 0) flag[0] = (cs < 128) ? 1 : 0;  // 1 = fp32, 0 = bf16
}

// ---------------- CSR build ----------------

__global__ __launch_bounds__(256) void hist_k(const int* __restrict__ rows, const int* __restrict__ cols,
                                              int* __restrict__ cnt, int E) {
    int e = blockIdx.x * 256 + threadIdx.x;
    if (e >= E) return;
    int r = rows[e], c = cols[e];
    if (r != c) atomicAdd(&cnt[r], 1);
}

__global__ __launch_bounds__(256) void dinv_k(const int* __restrict__ cnt, float* __restrict__ dinv, int n) {
    int i = blockIdx.x * 256 + threadIdx.x;
    if (i >= n) return;
    int d = cnt[i];
    dinv[i] = (d > 0) ? rsqrtf((float)d) : 0.f;
}

__global__ __launch_bounds__(256) void scan_block_k(const int* __restrict__ cnt, int* __restrict__ ptr,
                                                    int* __restrict__ bsum, int n) {
    __shared__ int s[256];
    int t = threadIdx.x;
    int i = blockIdx.x * 256 + t;
    int v = (i < n) ? cnt[i] : 0;
    s[t] = v;
    __syncthreads();
    for (int off = 1; off < 256; off <<= 1) {
        int x = (t >= off) ? s[t - off] : 0;
        __syncthreads();
        s[t] += x;
        __syncthreads();
    }
    if (i < n) ptr[i] = s[t] - v;  // exclusive within block
    if (t == 255) bsum[blockIdx.x] = s[255];
}

__global__ __launch_bounds__(1024) void scan_sums_k(int* __restrict__ bsum, int nb, int* __restrict__ ptr, int n) {
    __shared__ int s[1024];
    int t = threadIdx.x;
    int v = (t < nb) ? bsum[t] : 0;
    s[t] = v;
    __syncthreads();
    for (int off = 1; off < 1024; off <<= 1) {
        int x = (t >= off) ? s[t - off] : 0;
        __syncthreads();
        s[t] += x;
        __syncthreads();
    }
    if (t < nb) bsum[t] = s[t] - v;   // exclusive block offsets
    if (t == 1023) ptr[n] = s[1023];  // total non-self edges
}

__global__ __launch_bounds__(256) void scan_add_k(int* __restrict__ ptr, const int* __restrict__ bsum, int n) {
    int i = blockIdx.x * 256 + threadIdx.x;
    if (i < n) ptr[i] += bsum[blockIdx.x];
}

__global__ __launch_bounds__(256) void scatter_k(const int* __restrict__ rows, const int* __restrict__ cols,
                                                 const int* __restrict__ ptr, int* __restrict__ fill,
                                                 int* __restrict__ colS, int E) {
    int e = blockIdx.x * 256 + threadIdx.x;
    if (e >= E) return;
    int r = rows[e], c = cols[e];
    if (r == c) return;
    int p = atomicAdd(&fill[r], 1);
    colS[ptr[r] + p] = c;
}

// ---------------- feature staging ----------------

__global__ __launch_bounds__(256) void convert_x_k(const void* __restrict__ x, float* __restrict__ TxAll,
                                                   int n, const int* __restrict__ flag) {
    int isf = flag[0];
    int i = blockIdx.x * 256 + threadIdx.x;
    if (i >= n * 3) return;
    int r = i / 3, c = i - r * 3;
    float v;
    if (isf) v = ((const float*)x)[i];
    else     v = b2f(((const bf16*)x)[i]);
    TxAll[(size_t)r * 18 + c] = v;
}

// ---------------- propagation ----------------

__global__ __launch_bounds__(256) void prop_narrow_k(const int* __restrict__ ptr, const int* __restrict__ colS,
                                                     const float* __restrict__ dinv, const float* __restrict__ hin,
                                                     const float* __restrict__ sub, float* __restrict__ o,
                                                     int ld, int n, float alpha, int useSub) {
    int wv = threadIdx.x >> 6, lane = threadIdx.x & 63;
    int r = blockIdx.x * 4 + wv;
    if (r >= n) return;
    int s = ptr[r], e = ptr[r + 1];
    float dr = dinv[r];
    float a0 = 0.f, a1 = 0.f, a2 = 0.f;
    for (int idx = s + lane; idx < e; idx += 64) {
        int c = colS[idx];
        float nrm = -dr * dinv[c];
        const float* hp = hin + (size_t)c * ld;
        a0 += nrm * hp[0];
        a1 += nrm * hp[1];
        a2 += nrm * hp[2];
    }
    for (int off2 = 32; off2 > 0; off2 >>= 1) {
        a0 += __shfl_down(a0, off2);
        a1 += __shfl_down(a1, off2);
        a2 += __shfl_down(a2, off2);
    }
    if (lane == 0) {
        size_t b = (size_t)r * ld;
        float v0 = alpha * a0, v1 = alpha * a1, v2 = alpha * a2;
        if (useSub) { v0 -= sub[b + 0]; v1 -= sub[b + 1]; v2 -= sub[b + 2]; }
        o[b + 0] = v0; o[b + 1] = v1; o[b + 2] = v2;
    }
}

template <int VEC>
__global__ __launch_bounds__(256) void prop_wide_k(const int* __restrict__ ptr, const int* __restrict__ colS,
                                                   const float* __restrict__ dinv, const float* __restrict__ hin,
                                                   const float* __restrict__ sub, float* __restrict__ o,
                                                   int ld, int n, float alpha, int useSub) {
    int wv = threadIdx.x >> 6, lane = threadIdx.x & 63;
    int r = blockIdx.x * 4 + wv;
    if (r >= n) return;
    int s = ptr[r], e = ptr[r + 1];
    float dr = dinv[r];
    float acc[VEC];
#pragma unroll
    for (int v = 0; v < VEC; ++v) acc[v] = 0.f;
    for (int base = s; base < e; base += 64) {
        int idx = base + lane;
        int c = 0;
        float dc = 0.f;
        if (idx < e) { c = colS[idx]; dc = dinv[c]; }
        int cnt2 = e - base;
        if (cnt2 > 64) cnt2 = 64;
        for (int j = 0; j < cnt2; ++j) {
            int cc = __shfl(c, j);
            float nrm = -dr * __shfl(dc, j);
            const float* hp = hin + (size_t)cc * ld + lane;
#pragma unroll
            for (int v = 0; v < VEC; ++v) acc[v] += nrm * hp[v * 64];
        }
    }
    size_t rb = (size_t)r * ld + lane;
#pragma unroll
    for (int v = 0; v < VEC; ++v) {
        float val = alpha * acc[v];
        if (useSub) val -= sub[rb + v * 64];
        o[rb + v * 64] = val;
    }
}

// ---------------- GEMM: C = [C +] (A @ W[koff..]) [+ bias] [relu] ----------------
// flags: 1 = relu, 2 = accumulate into C, 4 = add bias. koff = W element offset.

__global__ __launch_bounds__(256) void gemm_k(const float* __restrict__ A, int lda,
                                              const void* __restrict__ W, size_t koff,
                                              const void* __restrict__ bias,
                                              float* __restrict__ C, int M, int N, int K, int flags,
                                              const int* __restrict__ flag) {
    __shared__ float As[16][65];
    __shared__ float Ws[16][64];
    int isf = flag[0];
    int t = threadIdx.x;
    int tn = t & 15, tm = t >> 4;
    int m0 = blockIdx.y * 64, n0 = blockIdx.x * 64;
    float acc[4][4] = {};
    for (int k0 = 0; k0 < K; k0 += 16) {
#pragma unroll
        for (int i = 0; i < 4; ++i) {
            int idx = i * 256 + t;
            int m = idx >> 4, k = idx & 15;
            int gm = m0 + m, gk = k0 + k;
            As[k][m] = (gm < M && gk < K) ? A[(size_t)gm * lda + gk] : 0.f;
        }
        if (isf) {
            const float* Wf = (const float*)W + koff;
#pragma unroll
            for (int i = 0; i < 4; ++i) {
                int idx = i * 256 + t;
                int k = idx >> 6, nn = idx & 63;
                int gk = k0 + k;
                Ws[k][nn] = (gk < K) ? Wf[(size_t)gk * N + n0 + nn] : 0.f;
            }
        } else {
            const bf16* Wh = (const bf16*)W + koff;
#pragma unroll
            for (int i = 0; i < 4; ++i) {
                int idx = i * 256 + t;
                int k = idx >> 6, nn = idx & 63;
                int gk = k0 + k;
                Ws[k][nn] = (gk < K) ? b2f(Wh[(size_t)gk * N + n0 + nn]) : 0.f;
            }
        }
        __syncthreads();
#pragma unroll
        for (int kk = 0; kk < 16; ++kk) {
            float a[4], b[4];
#pragma unroll
            for (int i = 0; i < 4; ++i) a[i] = As[kk][tm * 4 + i];
#pragma unroll
            for (int j = 0; j < 4; ++j) b[j] = Ws[kk][tn * 4 + j];
#pragma unroll
            for (int i = 0; i < 4; ++i)
#pragma unroll
                for (int j = 0; j < 4; ++j) acc[i][j] += a[i] * b[j];
        }
        __syncthreads();
    }
#pragma unroll
    for (int i = 0; i < 4; ++i) {
        int gm = m0 + tm * 4 + i;
        if (gm >= M) continue;
#pragma unroll
        for (int j = 0; j < 4; ++j) {
            int gn = n0 + tn * 4 + j;
            size_t ci = (size_t)gm * N + gn;
            float v = acc[i][j];
            if (flags & 4) {
                if (isf) v += ((const float*)bias)[gn];
                else     v += b2f(((const bf16*)bias)[gn]);
            }
            if (flags & 2) v += C[ci];
            if (flags & 1) v = fmaxf(v, 0.f);
            C[ci] = v;
        }
    }
}

// ---------------- pooling ----------------

__global__ __launch_bounds__(256) void pool_k(const float* __restrict__ in, const int* __restrict__ pcols,
                                              float* __restrict__ out, int n_out, int C, int ld) {
    int idx = blockIdx.x * 256 + threadIdx.x;
    if (idx >= n_out * C) return;
    int r = idx / C, ch = idx - r * C;
    const int* pc = pcols + (size_t)r * 4;
    float ssum = 0.f;
#pragma unroll
    for (int f = 0; f < 4; ++f) ssum += in[(size_t)pc[f] * C + ch];
    out[(size_t)r * ld + ch] = 0.25f * ssum;
}

// ---------------- final linear [10, 3.2M] ----------------

__global__ __launch_bounds__(256) void linear10_k(const float* __restrict__ h, const void* __restrict__ lw,
                                                  float* __restrict__ accum, int LIN, const int* __restrict__ flag) {
    int isf = flag[0];
    int lane = threadIdx.x & 63;
    float p[NCLS];
#pragma unroll
    for (int c = 0; c < NCLS; ++c) p[c] = 0.f;
    int stride = gridDim.x * blockDim.x;
    int i0 = blockIdx.x * blockDim.x + threadIdx.x;
    if (isf) {
        const float* lwf = (const float*)lw;
        for (int i = i0; i < LIN; i += stride) {
            float hv = h[i];
#pragma unroll
            for (int c = 0; c < NCLS; ++c) p[c] += hv * lwf[(size_t)c * LIN + i];
        }
    } else {
        const bf16* lwh = (const bf16*)lw;
        for (int i = i0; i < LIN; i += stride) {
            float hv = h[i];
#pragma unroll
            for (int c = 0; c < NCLS; ++c) p[c] += hv * b2f(lwh[(size_t)c * LIN + i]);
        }
    }
#pragma unroll
    for (int c = 0; c < NCLS; ++c) {
        float v = p[c];
        for (int off2 = 32; off2 > 0; off2 >>= 1) v += __shfl_down(v, off2);
        if (lane == 0) unsafeAtomicAdd(&accum[c], v);
    }
}

__global__ void finalize_k(const float* __restrict__ accum, const void* __restrict__ lb,
                           void* __restrict__ outp, const int* __restrict__ flag) {
    int isf = flag[0];
    int t = threadIdx.x;
    if (t < NCLS) {
        float lbv;
        if (isf) lbv = ((const float*)lb)[t];
        else     lbv = b2f(((const bf16*)lb)[t]);
        float v = accum[t] + lbv;
        if (isf) ((float*)outp)[t] = v;
        else     ((bf16*)outp)[t] = __float2bfloat16(v);
    }
}

__global__ void diag_k(void* __restrict__ outp, float val, const int* __restrict__ flag) {
    int isf = flag[0];
    int t = threadIdx.x;
    if (t < NCLS) {
        if (isf) ((float*)outp)[t] = val;
        else     ((bf16*)outp)[t] = __float2bfloat16(val);
    }
}

// ---------------- orchestration ----------------

extern "C" void kernel_launch(void* const* d_in, const int* in_sizes, int n_in,
                              void* d_out, int out_size, void* d_ws, size_t ws_size,
                              hipStream_t stream) {
    const void* x  = d_in[0];
    const int* ei0 = (const int*)d_in[1];
    const int* ei1 = (const int*)d_in[2];
    const int* ei2 = (const int*)d_in[3];
    const int* pc0 = (const int*)d_in[4];
    const int* pc1 = (const int*)d_in[5];
    const void* w0 = d_in[6];
    const void* b0 = d_in[7];
    const void* w1 = d_in[8];
    const void* b1 = d_in[9];
    const void* w2 = d_in[10];
    const void* b2 = d_in[11];
    const void* lw = d_in[12];
    const void* lb = d_in[13];

    const int E0 = in_sizes[1] / 2, E1 = in_sizes[2] / 2, E2 = in_sizes[3] / 2;

    // ---- workspace layout (117,604,608 B — known to fit from round 2's guard) ----
    char* base = (char*)d_ws;
    size_t off = 0;
    auto alloc = [&](size_t bytes) -> void* {
        void* p = base + off;
        off += (bytes + 255) & ~(size_t)255;
        return p;
    };
    float* TxAll = (float*)alloc((size_t)9600000 * 4);   // max(N0*18, 3*N1*64, N2*768)
    float* OutB  = (float*)alloc((size_t)12800000 * 4);  // max(N0*64, N1*128, N2*256)
    int*   colS  = (int*)alloc((size_t)6400000 * 4);     // max edges
    int*   ptr   = (int*)alloc((size_t)(N0 + 1) * 4);
    int*   cnt   = (int*)alloc((size_t)N0 * 4);          // reused as scatter fill
    float* dinv  = (float*)alloc((size_t)N0 * 4);
    int*   bsum  = (int*)alloc(4096);
    float* accum = (float*)alloc(64);                    // 256B slot: floats 0..9 accum; int at +64B = dtype flag
    int*   flag  = (int*)(accum + 16);

    detect_k<<<1, 256, 0, stream>>>((const unsigned int*)x, flag);

    const size_t NEED = 117604608;
    if (ws_size < NEED) {
        diag_k<<<1, 64, 0, stream>>>(d_out, (float)(ws_size >> 20), flag);
        return;
    }

    struct Lvl {
        int n, E, cin, cout;
        const int *rows, *cols;
        const void *w, *b;
        int relu;
    };
    Lvl L[3] = {
        {N0, E0, 3, 64, ei0, ei0 + E0, w0, b0, 1},
        {N1, E1, 64, 128, ei1, ei1 + E1, w1, b1, 1},
        {N2, E2, 128, 256, ei2, ei2 + E2, w2, b2, 0},
    };

    convert_x_k<<<(N0 * 3 + 255) / 256, 256, 0, stream>>>(x, TxAll, N0, flag);

    for (int li = 0; li < 3; ++li) {
        const Lvl& v = L[li];
        int n = v.n, E = v.E, cin = v.cin, cout = v.cout;
        int nb = (n + 255) / 256;
        int pgrid = (n + 3) / 4;

        // CSR build (self-loops excluded => row length == deg)
        hipMemsetAsync(cnt, 0, (size_t)n * 4, stream);
        hist_k<<<(E + 255) / 256, 256, 0, stream>>>(v.rows, v.cols, cnt, E);
        dinv_k<<<nb, 256, 0, stream>>>(cnt, dinv, n);
        scan_block_k<<<nb, 256, 0, stream>>>(cnt, ptr, bsum, n);
        scan_sums_k<<<1, 1024, 0, stream>>>(bsum, nb, ptr, n);
        scan_add_k<<<nb, 256, 0, stream>>>(ptr, bsum, n);
        hipMemsetAsync(cnt, 0, (size_t)n * 4, stream);
        scatter_k<<<(E + 255) / 256, 256, 0, stream>>>(v.rows, v.cols, ptr, cnt, colS, E);

        if (li != 1) {
            // fused layout: slot k at column k*cin, row stride ld = 6*cin
            int ld = KCH * cin;
            for (int k = 1; k < KCH; ++k) {
                const float* hin = TxAll + (size_t)(k - 1) * cin;
                const float* sub = (k >= 2) ? (TxAll + (size_t)(k - 2) * cin) : nullptr;
                float* o = TxAll + (size_t)k * cin;
                float alpha = (k >= 2) ? 2.f : 1.f;
                if (cin == 3)
                    prop_narrow_k<<<pgrid, 256, 0, stream>>>(ptr, colS, dinv, hin, sub, o, ld, n, alpha, k >= 2);
                else
                    prop_wide_k<2><<<pgrid, 256, 0, stream>>>(ptr, colS, dinv, hin, sub, o, ld, n, alpha, k >= 2);
            }
            dim3 gg(cout / 64, (n + 63) / 64);
            gemm_k<<<gg, 256, 0, stream>>>(TxAll, ld, v.w, 0, v.b, OutB, n, cout, ld, 4 | (v.relu ? 1 : 0), flag);
        } else {
            // rotating 3-slot layout (ld = 64), 6 accumulating GEMM passes
            float* S[3] = {TxAll, TxAll + (size_t)N1 * 64, TxAll + (size_t)2 * N1 * 64};
            dim3 gg(cout / 64, (n + 63) / 64);
            gemm_k<<<gg, 256, 0, stream>>>(S[0], 64, v.w, 0, v.b, OutB, n, cout, 64, 4, flag);
            for (int k = 1; k < KCH; ++k) {
                float* src = S[(k - 1) % 3];
                float* dst = S[k % 3];
                float* sub = (k >= 2) ? S[(k - 2) % 3] : nullptr;
                float alpha = (k >= 2) ? 2.f : 1.f;
                prop_wide_k<1><<<pgrid, 256, 0, stream>>>(ptr, colS, dinv, src, sub, dst, 64, n, alpha, k >= 2);
                int fl = 2 | ((k == KCH - 1 && v.relu) ? 1 : 0);
                gemm_k<<<gg, 256, 0, stream>>>(dst, 64, v.w, (size_t)k * 64 * cout, v.b, OutB, n, cout, 64, fl, flag);
            }
        }

        // pool into next level's Tx0
        if (li == 0)
            pool_k<<<(N1 * 64 + 255) / 256, 256, 0, stream>>>(OutB, pc0, TxAll, N1, 64, 64);
        else if (li == 1)
            pool_k<<<(N2 * 128 + 255) / 256, 256, 0, stream>>>(OutB, pc1, TxAll, N2, 128, KCH * 128);
    }

    hipMemsetAsync(accum, 0, 64, stream);
    linear10_k<<<1024, 256, 0, stream>>>(OutB, lw, accum, N2 * 256, flag);
    finalize_k<<<1, 64, 0, stream>>>(accum, lb, d_out, flag);
}

// Round 4
// 2392.397 us; speedup vs baseline: 1.3448x; 1.3448x over previous
//
#include <hip/hip_runtime.h>
#include <hip/hip_bf16.h>

// ChebNet classifier: 3x ChebConv(K=6) + pool + linear. fp32 internal.
// Round 4: (1) linear10 rewritten — vectorized bf16 loads + block reduction,
// 1 atomic/block (was 40960 same-line atomics = 554us tail); (2) prop_wide
// inner loop unrolled x4 for memory-level parallelism; (3) level-1 restored
// to fused 6-slot layout (ws is ~500MB) — single K=384 GEMM, no OutB sweeps.

#define N0 200000
#define N1 50000
#define N2 12500
#define KCH 6
#define NCLS 10

typedef __hip_bfloat16 bf16;
static __device__ __forceinline__ float b2f(bf16 v) { return __bfloat162float(v); }
static __device__ __forceinline__ float blo(unsigned u) { return __uint_as_float(u << 16); }
static __device__ __forceinline__ float bhi(unsigned u) { return __uint_as_float(u & 0xFFFF0000u); }

// ---------------- dtype detection (1 = fp32, 0 = bf16) ----------------
__global__ void detect_k(const unsigned int* __restrict__ xb, int* __restrict__ flag) {
    __shared__ int cs;
    int t = threadIdx.x;
    if (t == 0) cs = 0;
    __syncthreads();
    unsigned w = xb[t];
    unsigned e = (w >> 7) & 0xFFu;
    if (e >= 0x30u && e <= 0x43u) atomicAdd(&cs, 1);
    __syncthreads();
    if (t == 0) flag[0] = (cs < 128) ? 1 : 0;
}

// ---------------- CSR build ----------------

__global__ __launch_bounds__(256) void hist_k(const int* __restrict__ rows, const int* __restrict__ cols,
                                              int* __restrict__ cnt, int E) {
    int e = blockIdx.x * 256 + threadIdx.x;
    if (e >= E) return;
    int r = rows[e], c = cols[e];
    if (r != c) atomicAdd(&cnt[r], 1);
}

__global__ __launch_bounds__(256) void dinv_k(const int* __restrict__ cnt, float* __restrict__ dinv, int n) {
    int i = blockIdx.x * 256 + threadIdx.x;
    if (i >= n) return;
    int d = cnt[i];
    dinv[i] = (d > 0) ? rsqrtf((float)d) : 0.f;
}

__global__ __launch_bounds__(256) void scan_block_k(const int* __restrict__ cnt, int* __restrict__ ptr,
                                                    int* __restrict__ bsum, int n) {
    __shared__ int s[256];
    int t = threadIdx.x;
    int i = blockIdx.x * 256 + t;
    int v = (i < n) ? cnt[i] : 0;
    s[t] = v;
    __syncthreads();
    for (int off = 1; off < 256; off <<= 1) {
        int x = (t >= off) ? s[t - off] : 0;
        __syncthreads();
        s[t] += x;
        __syncthreads();
    }
    if (i < n) ptr[i] = s[t] - v;  // exclusive within block
    if (t == 255) bsum[blockIdx.x] = s[255];
}

__global__ __launch_bounds__(1024) void scan_sums_k(int* __restrict__ bsum, int nb, int* __restrict__ ptr, int n) {
    __shared__ int s[1024];
    int t = threadIdx.x;
    int v = (t < nb) ? bsum[t] : 0;
    s[t] = v;
    __syncthreads();
    for (int off = 1; off < 1024; off <<= 1) {
        int x = (t >= off) ? s[t - off] : 0;
        __syncthreads();
        s[t] += x;
        __syncthreads();
    }
    if (t < nb) bsum[t] = s[t] - v;   // exclusive block offsets
    if (t == 1023) ptr[n] = s[1023];  // total non-self edges
}

__global__ __launch_bounds__(256) void scan_add_k(int* __restrict__ ptr, const int* __restrict__ bsum, int n) {
    int i = blockIdx.x * 256 + threadIdx.x;
    if (i < n) ptr[i] += bsum[blockIdx.x];
}

__global__ __launch_bounds__(256) void scatter_k(const int* __restrict__ rows, const int* __restrict__ cols,
                                                 const int* __restrict__ ptr, int* __restrict__ fill,
                                                 int* __restrict__ colS, int E) {
    int e = blockIdx.x * 256 + threadIdx.x;
    if (e >= E) return;
    int r = rows[e], c = cols[e];
    if (r == c) return;
    int p = atomicAdd(&fill[r], 1);
    colS[ptr[r] + p] = c;
}

// ---------------- feature staging ----------------

__global__ __launch_bounds__(256) void convert_x_k(const void* __restrict__ x, float* __restrict__ TxAll,
                                                   int n, const int* __restrict__ flag) {
    int isf = flag[0];
    int i = blockIdx.x * 256 + threadIdx.x;
    if (i >= n * 3) return;
    int r = i / 3, c = i - r * 3;
    float v;
    if (isf) v = ((const float*)x)[i];
    else     v = b2f(((const bf16*)x)[i]);
    TxAll[(size_t)r * 18 + c] = v;
}

// ---------------- propagation ----------------

__global__ __launch_bounds__(256) void prop_narrow_k(const int* __restrict__ ptr, const int* __restrict__ colS,
                                                     const float* __restrict__ dinv, const float* __restrict__ hin,
                                                     const float* __restrict__ sub, float* __restrict__ o,
                                                     int ld, int n, float alpha, int useSub) {
    int wv = threadIdx.x >> 6, lane = threadIdx.x & 63;
    int r = blockIdx.x * 4 + wv;
    if (r >= n) return;
    int s = ptr[r], e = ptr[r + 1];
    float dr = dinv[r];
    float a0 = 0.f, a1 = 0.f, a2 = 0.f;
    for (int idx = s + lane; idx < e; idx += 64) {
        int c = colS[idx];
        float nrm = -dr * dinv[c];
        const float* hp = hin + (size_t)c * ld;
        a0 += nrm * hp[0];
        a1 += nrm * hp[1];
        a2 += nrm * hp[2];
    }
    for (int off2 = 32; off2 > 0; off2 >>= 1) {
        a0 += __shfl_down(a0, off2);
        a1 += __shfl_down(a1, off2);
        a2 += __shfl_down(a2, off2);
    }
    if (lane == 0) {
        size_t b = (size_t)r * ld;
        float v0 = alpha * a0, v1 = alpha * a1, v2 = alpha * a2;
        if (useSub) { v0 -= sub[b + 0]; v1 -= sub[b + 1]; v2 -= sub[b + 2]; }
        o[b + 0] = v0; o[b + 1] = v1; o[b + 2] = v2;
    }
}

// cin == 64*VEC: wave per row, lane = channel; edges shfl-broadcast; x4 unroll
// so 4 independent row-gathers are in flight per stall (was 1 -> L2-latency bound).
template <int VEC>
__global__ __launch_bounds__(256) void prop_wide_k(const int* __restrict__ ptr, const int* __restrict__ colS,
                                                   const float* __restrict__ dinv, const float* __restrict__ hin,
                                                   const float* __restrict__ sub, float* __restrict__ o,
                                                   int ld, int n, float alpha, int useSub) {
    int wv = threadIdx.x >> 6, lane = threadIdx.x & 63;
    int r = blockIdx.x * 4 + wv;
    if (r >= n) return;
    int s = ptr[r], e = ptr[r + 1];
    float dr = dinv[r];
    float acc[VEC];
#pragma unroll
    for (int v = 0; v < VEC; ++v) acc[v] = 0.f;
    for (int base = s; base < e; base += 64) {
        int idx = base + lane;
        int c = 0;
        float dc = 0.f;
        if (idx < e) { c = colS[idx]; dc = dinv[c]; }
        int cnt2 = e - base;
        if (cnt2 > 64) cnt2 = 64;
        int j = 0;
        for (; j + 4 <= cnt2; j += 4) {
            int cc0 = __shfl(c, j), cc1 = __shfl(c, j + 1), cc2 = __shfl(c, j + 2), cc3 = __shfl(c, j + 3);
            float n0 = -dr * __shfl(dc, j), n1 = -dr * __shfl(dc, j + 1);
            float n2 = -dr * __shfl(dc, j + 2), n3 = -dr * __shfl(dc, j + 3);
            const float* h0 = hin + (size_t)cc0 * ld + lane;
            const float* h1 = hin + (size_t)cc1 * ld + lane;
            const float* h2 = hin + (size_t)cc2 * ld + lane;
            const float* h3 = hin + (size_t)cc3 * ld + lane;
            float v0[VEC], v1[VEC], v2[VEC], v3[VEC];
#pragma unroll
            for (int v = 0; v < VEC; ++v) { v0[v] = h0[v * 64]; v1[v] = h1[v * 64]; v2[v] = h2[v * 64]; v3[v] = h3[v * 64]; }
#pragma unroll
            for (int v = 0; v < VEC; ++v) acc[v] += n0 * v0[v] + n1 * v1[v] + n2 * v2[v] + n3 * v3[v];
        }
        for (; j < cnt2; ++j) {
            int cc = __shfl(c, j);
            float nrm = -dr * __shfl(dc, j);
            const float* hp = hin + (size_t)cc * ld + lane;
#pragma unroll
            for (int v = 0; v < VEC; ++v) acc[v] += nrm * hp[v * 64];
        }
    }
    size_t rb = (size_t)r * ld + lane;
#pragma unroll
    for (int v = 0; v < VEC; ++v) {
        float val = alpha * acc[v];
        if (useSub) val -= sub[rb + v * 64];
        o[rb + v * 64] = val;
    }
}

// ---------------- GEMM: C = [C +] (A @ W[koff..]) [+ bias] [relu] ----------------
// flags: 1 = relu, 2 = accumulate into C, 4 = add bias. koff = W element offset.

__global__ __launch_bounds__(256) void gemm_k(const float* __restrict__ A, int lda,
                                              const void* __restrict__ W, size_t koff,
                                              const void* __restrict__ bias,
                                              float* __restrict__ C, int M, int N, int K, int flags,
                                              const int* __restrict__ flag) {
    __shared__ float As[16][65];
    __shared__ float Ws[16][64];
    int isf = flag[0];
    int t = threadIdx.x;
    int tn = t & 15, tm = t >> 4;
    int m0 = blockIdx.y * 64, n0 = blockIdx.x * 64;
    float acc[4][4] = {};
    for (int k0 = 0; k0 < K; k0 += 16) {
#pragma unroll
        for (int i = 0; i < 4; ++i) {
            int idx = i * 256 + t;
            int m = idx >> 4, k = idx & 15;
            int gm = m0 + m, gk = k0 + k;
            As[k][m] = (gm < M && gk < K) ? A[(size_t)gm * lda + gk] : 0.f;
        }
        if (isf) {
            const float* Wf = (const float*)W + koff;
#pragma unroll
            for (int i = 0; i < 4; ++i) {
                int idx = i * 256 + t;
                int k = idx >> 6, nn = idx & 63;
                int gk = k0 + k;
                Ws[k][nn] = (gk < K) ? Wf[(size_t)gk * N + n0 + nn] : 0.f;
            }
        } else {
            const bf16* Wh = (const bf16*)W + koff;
#pragma unroll
            for (int i = 0; i < 4; ++i) {
                int idx = i * 256 + t;
                int k = idx >> 6, nn = idx & 63;
                int gk = k0 + k;
                Ws[k][nn] = (gk < K) ? b2f(Wh[(size_t)gk * N + n0 + nn]) : 0.f;
            }
        }
        __syncthreads();
#pragma unroll
        for (int kk = 0; kk < 16; ++kk) {
            float a[4], b[4];
#pragma unroll
            for (int i = 0; i < 4; ++i) a[i] = As[kk][tm * 4 + i];
#pragma unroll
            for (int j = 0; j < 4; ++j) b[j] = Ws[kk][tn * 4 + j];
#pragma unroll
            for (int i = 0; i < 4; ++i)
#pragma unroll
                for (int j = 0; j < 4; ++j) acc[i][j] += a[i] * b[j];
        }
        __syncthreads();
    }
#pragma unroll
    for (int i = 0; i < 4; ++i) {
        int gm = m0 + tm * 4 + i;
        if (gm >= M) continue;
#pragma unroll
        for (int j = 0; j < 4; ++j) {
            int gn = n0 + tn * 4 + j;
            size_t ci = (size_t)gm * N + gn;
            float v = acc[i][j];
            if (flags & 4) {
                if (isf) v += ((const float*)bias)[gn];
                else     v += b2f(((const bf16*)bias)[gn]);
            }
            if (flags & 2) v += C[ci];
            if (flags & 1) v = fmaxf(v, 0.f);
            C[ci] = v;
        }
    }
}

// ---------------- pooling ----------------

__global__ __launch_bounds__(256) void pool_k(const float* __restrict__ in, const int* __restrict__ pcols,
                                              float* __restrict__ out, int n_out, int C, int ld) {
    int idx = blockIdx.x * 256 + threadIdx.x;
    if (idx >= n_out * C) return;
    int r = idx / C, ch = idx - r * C;
    const int* pc = pcols + (size_t)r * 4;
    float ssum = 0.f;
#pragma unroll
    for (int f = 0; f < 4; ++f) ssum += in[(size_t)pc[f] * C + ch];
    out[(size_t)r * ld + ch] = 0.25f * ssum;
}

// ---------------- final linear: out[c] = lw[c,:] . h  ----------------
// grid (gx, NCLS); vector 16B loads; block-reduce; ONE atomic per block.

__global__ __launch_bounds__(256) void linear10_k(const float* __restrict__ h, const void* __restrict__ lw,
                                                  float* __restrict__ accum, int LIN, const int* __restrict__ flag) {
    int isf = flag[0];
    int c = blockIdx.y;
    int t = threadIdx.x;
    int nvec = LIN >> 3;  // groups of 8 elements
    int stride = gridDim.x * 256;
    float p = 0.f;
    const float4* h4 = (const float4*)h;
    if (isf) {
        const float4* lw4 = (const float4*)lw + (size_t)c * (LIN >> 2);
        for (int i = blockIdx.x * 256 + t; i < nvec; i += stride) {
            float4 a0 = h4[2 * i], a1 = h4[2 * i + 1];
            float4 b0 = lw4[2 * i], b1 = lw4[2 * i + 1];
            p += a0.x * b0.x + a0.y * b0.y + a0.z * b0.z + a0.w * b0.w
               + a1.x * b1.x + a1.y * b1.y + a1.z * b1.z + a1.w * b1.w;
        }
    } else {
        const uint4* lwv = (const uint4*)lw + (size_t)c * nvec;
        for (int i = blockIdx.x * 256 + t; i < nvec; i += stride) {
            uint4 w4 = lwv[i];
            float4 a0 = h4[2 * i], a1 = h4[2 * i + 1];
            p += a0.x * blo(w4.x) + a0.y * bhi(w4.x)
               + a0.z * blo(w4.y) + a0.w * bhi(w4.y)
               + a1.x * blo(w4.z) + a1.y * bhi(w4.z)
               + a1.z * blo(w4.w) + a1.w * bhi(w4.w);
        }
    }
    for (int off2 = 32; off2 > 0; off2 >>= 1) p += __shfl_down(p, off2);
    __shared__ float wsum[4];
    int wv = t >> 6, lane = t & 63;
    if (lane == 0) wsum[wv] = p;
    __syncthreads();
    if (t == 0) unsafeAtomicAdd(&accum[c], wsum[0] + wsum[1] + wsum[2] + wsum[3]);
}

__global__ void finalize_k(const float* __restrict__ accum, const void* __restrict__ lb,
                           void* __restrict__ outp, const int* __restrict__ flag) {
    int isf = flag[0];
    int t = threadIdx.x;
    if (t < NCLS) {
        float lbv;
        if (isf) lbv = ((const float*)lb)[t];
        else     lbv = b2f(((const bf16*)lb)[t]);
        float v = accum[t] + lbv;
        if (isf) ((float*)outp)[t] = v;
        else     ((bf16*)outp)[t] = __float2bfloat16(v);
    }
}

__global__ void diag_k(void* __restrict__ outp, float val, const int* __restrict__ flag) {
    int isf = flag[0];
    int t = threadIdx.x;
    if (t < NCLS) {
        if (isf) ((float*)outp)[t] = val;
        else     ((bf16*)outp)[t] = __float2bfloat16(val);
    }
}

// ---------------- orchestration ----------------

extern "C" void kernel_launch(void* const* d_in, const int* in_sizes, int n_in,
                              void* d_out, int out_size, void* d_ws, size_t ws_size,
                              hipStream_t stream) {
    const void* x  = d_in[0];
    const int* ei0 = (const int*)d_in[1];
    const int* ei1 = (const int*)d_in[2];
    const int* ei2 = (const int*)d_in[3];
    const int* pc0 = (const int*)d_in[4];
    const int* pc1 = (const int*)d_in[5];
    const void* w0 = d_in[6];
    const void* b0 = d_in[7];
    const void* w1 = d_in[8];
    const void* b1 = d_in[9];
    const void* w2 = d_in[10];
    const void* b2 = d_in[11];
    const void* lw = d_in[12];
    const void* lb = d_in[13];

    const int E0 = in_sizes[1] / 2, E1 = in_sizes[2] / 2, E2 = in_sizes[3] / 2;

    // ---- workspace layout (156,004,608 B; ws is ~500 MB per harness poison) ----
    char* base = (char*)d_ws;
    size_t off = 0;
    auto alloc = [&](size_t bytes) -> void* {
        void* p = base + off;
        off += (bytes + 255) & ~(size_t)255;
        return p;
    };
    float* TxAll = (float*)alloc((size_t)19200000 * 4);  // max(N0*18, N1*384, N2*768)
    float* OutB  = (float*)alloc((size_t)12800000 * 4);  // max(N0*64, N1*128, N2*256)
    int*   colS  = (int*)alloc((size_t)6400000 * 4);     // max edges
    int*   ptr   = (int*)alloc((size_t)(N0 + 1) * 4);
    int*   cnt   = (int*)alloc((size_t)N0 * 4);          // reused as scatter fill
    float* dinv  = (float*)alloc((size_t)N0 * 4);
    int*   bsum  = (int*)alloc(4096);
    float* accum = (float*)alloc(64);                    // floats 0..9; int at +64B = dtype flag
    int*   flag  = (int*)(accum + 16);

    detect_k<<<1, 256, 0, stream>>>((const unsigned int*)x, flag);

    const size_t NEED = 156004608;
    if (ws_size < NEED) {
        diag_k<<<1, 64, 0, stream>>>(d_out, (float)(ws_size >> 20), flag);
        return;
    }

    struct Lvl {
        int n, E, cin, cout;
        const int *rows, *cols;
        const void *w, *b;
        int relu;
    };
    Lvl L[3] = {
        {N0, E0, 3, 64, ei0, ei0 + E0, w0, b0, 1},
        {N1, E1, 64, 128, ei1, ei1 + E1, w1, b1, 1},
        {N2, E2, 128, 256, ei2, ei2 + E2, w2, b2, 0},
    };

    convert_x_k<<<(N0 * 3 + 255) / 256, 256, 0, stream>>>(x, TxAll, N0, flag);

    for (int li = 0; li < 3; ++li) {
        const Lvl& v = L[li];
        int n = v.n, E = v.E, cin = v.cin, cout = v.cout;
        int nb = (n + 255) / 256;
        int pgrid = (n + 3) / 4;
        int ld = KCH * cin;

        // CSR build (self-loops excluded => row length == deg)
        hipMemsetAsync(cnt, 0, (size_t)n * 4, stream);
        hist_k<<<(E + 255) / 256, 256, 0, stream>>>(v.rows, v.cols, cnt, E);
        dinv_k<<<nb, 256, 0, stream>>>(cnt, dinv, n);
        scan_block_k<<<nb, 256, 0, stream>>>(cnt, ptr, bsum, n);
        scan_sums_k<<<1, 1024, 0, stream>>>(bsum, nb, ptr, n);
        scan_add_k<<<nb, 256, 0, stream>>>(ptr, bsum, n);
        hipMemsetAsync(cnt, 0, (size_t)n * 4, stream);
        scatter_k<<<(E + 255) / 256, 256, 0, stream>>>(v.rows, v.cols, ptr, cnt, colS, E);

        // Chebyshev recurrence into fused slots (slot k at column k*cin, row stride ld)
        for (int k = 1; k < KCH; ++k) {
            const float* hin = TxAll + (size_t)(k - 1) * cin;
            const float* sub = (k >= 2) ? (TxAll + (size_t)(k - 2) * cin) : nullptr;
            float* o = TxAll + (size_t)k * cin;
            float alpha = (k >= 2) ? 2.f : 1.f;
            if (cin == 3)
                prop_narrow_k<<<pgrid, 256, 0, stream>>>(ptr, colS, dinv, hin, sub, o, ld, n, alpha, k >= 2);
            else if (cin == 64)
                prop_wide_k<1><<<pgrid, 256, 0, stream>>>(ptr, colS, dinv, hin, sub, o, ld, n, alpha, k >= 2);
            else
                prop_wide_k<2><<<pgrid, 256, 0, stream>>>(ptr, colS, dinv, hin, sub, o, ld, n, alpha, k >= 2);
        }

        // fused 6-slot GEMM: OutB[n,cout] = TxAll[n,ld] @ w[ld,cout] + bias (+relu)
        dim3 gg(cout / 64, (n + 63) / 64);
        gemm_k<<<gg, 256, 0, stream>>>(TxAll, ld, v.w, 0, v.b, OutB, n, cout, ld, 4 | (v.relu ? 1 : 0), flag);

        // pool into next level's slot0
        if (li == 0)
            pool_k<<<(N1 * 64 + 255) / 256, 256, 0, stream>>>(OutB, pc0, TxAll, N1, 64, KCH * 64);
        else if (li == 1)
            pool_k<<<(N2 * 128 + 255) / 256, 256, 0, stream>>>(OutB, pc1, TxAll, N2, 128, KCH * 128);
    }

    hipMemsetAsync(accum, 0, 64, stream);
    {
        dim3 lg(128, NCLS);
        linear10_k<<<lg, 256, 0, stream>>>(OutB, lw, accum, N2 * 256, flag);
    }
    finalize_k<<<1, 64, 0, stream>>>(accum, lb, d_out, flag);
}